// Round 9
// baseline (4106.659 us; speedup 1.0000x reference)
//
#include <hip/hip_runtime.h>
#include <hip/hip_bf16.h>

// LSTM-LL v9: v7's spill-free streamed-weight loop, re-tiled to 16 batch
// rows/block x 512 blocks -> ~15 KB LDS -> 2 blocks/CU, 4 waves/SIMD.
// All weights (whh1/whh2/wih2/wout) stream from pre-scaled bf16 tables with
// per-use inline loads; latency hidden by doubled wave count + block overlap.
// B=8192, T=128, E=128, V=128, L=2. 512 blocks x 512 thr.

typedef __bf16 bf16x8 __attribute__((ext_vector_type(8)));
typedef __bf16 bf16x4 __attribute__((ext_vector_type(4)));
typedef float  f32x4  __attribute__((ext_vector_type(4)));

#define LOG2E 1.4426950408889634f
#define LN2   0.6931471805599453f

static __device__ __bf16 g_emb1[128 * 512];       // [v][gate*128+e] = (emb@Wih1^T + b1)*rowscale
static __device__ __bf16 g_woutbf[128 * 128];     // [v][e] * LOG2E
static __device__ __bf16 g_whhbf[2 * 512 * 128];  // [l][gate*128+col][k] * rowscale
static __device__ __bf16 g_wih2bf[512 * 128];     // [gate*128+col][k] * rowscale (layer 2)

__device__ __forceinline__ float frcp(float x) {
#if __has_builtin(__builtin_amdgcn_rcpf)
  return __builtin_amdgcn_rcpf(x);
#else
  return 1.0f / x;
#endif
}
__device__ __forceinline__ float fexp2(float x) {
#if __has_builtin(__builtin_amdgcn_exp2f)
  return __builtin_amdgcn_exp2f(x);
#else
  return exp2f(x);
#endif
}
__device__ __forceinline__ float flog2(float x) {
#if __has_builtin(__builtin_amdgcn_logf)
  return __builtin_amdgcn_logf(x);
#else
  return log2f(x);
#endif
}

// rotation swizzle for [*][128] bf16 LDS tiles: e -> (e + 8*(row&15)) & 127
__device__ __forceinline__ int hoff(int row, int e) {
  return row * 128 + ((e + ((row & 15) << 3)) & 127);
}

__global__ void prep_emb1(const float* __restrict__ emb, const float* __restrict__ Wih,
                          const float* __restrict__ bih, const float* __restrict__ bhh,
                          const float* __restrict__ Wout, const float* __restrict__ Whh) {
  __shared__ float embS[128 * 128];
  __shared__ float wS[32 * 128];
  const int tid = threadIdx.x, bc = blockIdx.x;
  for (int i = tid; i < 128 * 32; i += 512) ((f32x4*)embS)[i] = ((const f32x4*)emb)[i];
  for (int i = tid; i < 32 * 32; i += 512)
    ((f32x4*)wS)[i] = ((const f32x4*)(Wih + bc * 32 * 128))[i];
  {  // bf16 W_out table (pre-scaled by log2e)
    int idx = bc * 512 + tid;
    g_woutbf[idx * 2]     = (__bf16)(Wout[idx * 2] * LOG2E);
    g_woutbf[idx * 2 + 1] = (__bf16)(Wout[idx * 2 + 1] * LOG2E);
  }
  // bf16 Whh table (both layers) + Wih layer-2, pre-scaled per gate (g-gate x2)
  for (int i = bc * 512 + tid; i < 2 * 512 * 128; i += 16 * 512) {
    int gate = (i >> 14) & 3;
    float sc = (gate == 2) ? 2.0f * LOG2E : LOG2E;
    g_whhbf[i] = (__bf16)(Whh[i] * sc);
  }
  for (int i = bc * 512 + tid; i < 512 * 128; i += 16 * 512) {
    int gate = (i >> 14) & 3;
    float sc = (gate == 2) ? 2.0f * LOG2E : LOG2E;
    g_wih2bf[i] = (__bf16)(Wih[512 * 128 + i] * sc);
  }
  __syncthreads();
  const int v = tid & 127, c0 = (tid >> 7) * 8;
  const int rot = v & 31;
#pragma unroll
  for (int j = 0; j < 8; ++j) {
    int c = c0 + j;
    float s = 0.f;
    for (int k = 0; k < 128; ++k) {
      int kk = (k + rot) & 127;
      s += embS[v * 128 + kk] * wS[c * 128 + kk];
    }
    int col = bc * 32 + c;
    float sc = ((col >> 7) == 2) ? 2.0f * LOG2E : LOG2E;
    g_emb1[v * 512 + col] = (__bf16)((s + bih[col] + bhh[col]) * sc);
  }
}

__global__ __launch_bounds__(512, 4) void lstm_ll(
    const float* __restrict__ state, const int* __restrict__ tokens,
    const float* __restrict__ W_ih, const float* __restrict__ b_ih,
    const float* __restrict__ b_hh, const float* __restrict__ b_out,
    float* __restrict__ out) {
  __shared__ __align__(16) __bf16 h1L[2][16 * 128];  // 8 KB dbuf
  __shared__ __align__(16) __bf16 h2L[16 * 128];     // 4 KB
  __shared__ unsigned char tokL[128][16];            // 2 KB [t][r]
  __shared__ float wsum[8][16];                      // 512 B
  __shared__ float llL[16];

  const int tid  = threadIdx.x;
  const int w    = tid >> 6;       // 0..7 (gate-col block)
  const int lane = tid & 63;
  const int lr   = lane & 15;
  const int lh   = lane >> 4;
  const int b0   = blockIdx.x * 16;
  const int col  = w * 16 + lr;      // gate-row index (MFMA A-frag m = lr)
  const int koff = lh * 8;           // k offset within a 32-chunk
  const int e0   = w * 16 + lh * 4;  // lane's 4 hidden units in D-frags
  const int brow = lr;               // lane's batch row
  const float gscA[4] = {LOG2E, LOG2E, 2.0f * LOG2E, LOG2E};

  // ---- one-time staging ----
  for (int i = tid; i < 16 * 128; i += 512) {
    int r = i & 15, t = i >> 4;
    tokL[t][r] = (unsigned char)tokens[(b0 + r) * 128 + t];
  }
  if (tid < 16) llL[tid] = 0.0f;

  auto ldw8s = [&](const float* p, float sc) -> bf16x8 {
    f32x4 x0 = *(const f32x4*)p, x1 = *(const f32x4*)(p + 4);
    bf16x8 v;
#pragma unroll
    for (int j = 0; j < 4; ++j) { v[j] = (__bf16)(x0[j] * sc); v[4 + j] = (__bf16)(x1[j] * sc); }
    return v;
  };

  f32x4 bias2v4[4], bo4;
#pragma unroll
  for (int gg = 0; gg < 4; ++gg)
#pragma unroll
    for (int j = 0; j < 4; ++j)
      bias2v4[gg][j] = (b_ih[512 + gg * 128 + e0 + j] + b_hh[512 + gg * 128 + e0 + j]) * gscA[gg];
#pragma unroll
  for (int j = 0; j < 4; ++j) bo4[j] = b_out[e0 + j] * LOG2E;

  float c1[4] = {}, c2[4] = {};

  auto ldB = [&](const __bf16* buf, int kc) -> bf16x8 {
    return *(const bf16x8*)(buf + hoff(brow, kc * 32 + koff));
  };

  f32x4 acc[4];
  auto zacc = [&]() {
#pragma unroll
    for (int gg = 0; gg < 4; ++gg) acc[gg] = f32x4{0.f, 0.f, 0.f, 0.f};
  };

  auto elem = [&](const f32x4* b4, float (&c)[4], __bf16* hout) {
    bf16x4 hp;
#pragma unroll
    for (int j = 0; j < 4; ++j) {
      float gi = acc[0][j] + b4[0][j];
      float gf = acc[1][j] + b4[1][j];
      float gc = acc[2][j] + b4[2][j];
      float go = acc[3][j] + b4[3][j];
      float sf = frcp(1.f + fexp2(-gf));
      float si = frcp(1.f + fexp2(-gi));
      float tg = 1.f - 2.f * frcp(fexp2(gc) + 1.f);
      float cc = sf * c[j] + si * tg;
      c[j] = cc;
      float so = frcp(1.f + fexp2(-go));
      float tc = 1.f - 2.f * frcp(fexp2(2.f * LOG2E * cc) + 1.f);
      hp[j] = (__bf16)(so * tc);
    }
    *(bf16x4*)(hout + hoff(brow, e0)) = hp;
  };
  const f32x4 zf4 = {0.f, 0.f, 0.f, 0.f};
  const f32x4 zb4[4] = {zf4, zf4, zf4, zf4};

  __syncthreads();  // staging complete

  bf16x4 gv[4];  // layer-1 per-token gate rows for this lane's batch row
  auto gather = [&](int t) {
    int tk = (int)tokL[t][brow];
    const __bf16* pp = g_emb1 + tk * 512 + e0;
#pragma unroll
    for (int gg = 0; gg < 4; ++gg) gv[gg] = *(const bf16x4*)(pp + gg * 128);
  };
  gather(0);

  // ---- init step (x = state, h = c = 0); h0_l1 -> h1L[0], h0_l2 -> h2L ----
  {
    zacc();
#pragma unroll
    for (int kc = 0; kc < 4; ++kc) {
      bf16x8 s0 = ldw8s(state + (size_t)(b0 + brow) * 128 + kc * 32 + koff, 1.0f);
#pragma unroll
      for (int gg = 0; gg < 4; ++gg) {
        bf16x8 a = ldw8s(W_ih + (gg * 128 + col) * 128 + kc * 32 + koff, gscA[gg]);
        acc[gg] = __builtin_amdgcn_mfma_f32_16x16x32_bf16(a, s0, acc[gg], 0, 0, 0);
      }
    }
    f32x4 bias1v4[4];
#pragma unroll
    for (int gg = 0; gg < 4; ++gg)
#pragma unroll
      for (int j = 0; j < 4; ++j)
        bias1v4[gg][j] = (b_ih[gg * 128 + e0 + j] + b_hh[gg * 128 + e0 + j]) * gscA[gg];
    elem(bias1v4, c1, h1L[0]);
    __syncthreads();
    zacc();  // layer-2 init: Wih2 x h1 only (h2 = 0)
#pragma unroll
    for (int kc = 0; kc < 4; ++kc) {
      bf16x8 x0 = ldB(h1L[0], kc);
#pragma unroll
      for (int gg = 0; gg < 4; ++gg) {
        bf16x8 a = *(const bf16x8*)(g_wih2bf + (size_t)(gg * 128 + col) * 128 + kc * 32 + koff);
        acc[gg] = __builtin_amdgcn_mfma_f32_16x16x32_bf16(a, x0, acc[gg], 0, 0, 0);
      }
    }
    elem(bias2v4, c2, h2L);
    __syncthreads();
  }

  f32x4 lv;  // log2-domain logits of step t-1 for this lane's batch row

  // ---- main loop (v7 shape, 3 barriers/step) ----
#pragma unroll 1
  for (int t = 0; t <= 127; ++t) {
    const bool act = (t < 127), pend = (t > 0);
    const __bf16* h1p = h1L[t & 1];
    __bf16* h1c = h1L[(t & 1) ^ 1];

    // -------- Phase A --------
    if (pend) {
      f32x4 la = zf4;
#pragma unroll
      for (int kc = 0; kc < 4; ++kc) {
        bf16x8 wo = *(const bf16x8*)(g_woutbf + col * 128 + kc * 32 + koff);
        bf16x8 y0 = ldB(h2L, kc);
        la = __builtin_amdgcn_mfma_f32_16x16x32_bf16(wo, y0, la, 0, 0, 0);
      }
      lv = la + bo4;
    }
    if (act) {
#pragma unroll
      for (int gg = 0; gg < 4; ++gg)
#pragma unroll
        for (int j = 0; j < 4; ++j) acc[gg][j] = (float)gv[gg][j];
#pragma unroll
      for (int kc = 0; kc < 4; ++kc) {
        bf16x8 p0 = ldB(h1p, kc);
#pragma unroll
        for (int gg = 0; gg < 4; ++gg) {
          bf16x8 a = *(const bf16x8*)(g_whhbf + (size_t)(gg * 128 + col) * 128 + kc * 32 + koff);
          acc[gg] = __builtin_amdgcn_mfma_f32_16x16x32_bf16(a, p0, acc[gg], 0, 0, 0);
        }
      }
    }
    if (pend) {
      float s0 = fexp2(lv[0]) + fexp2(lv[1]) + fexp2(lv[2]) + fexp2(lv[3]);
      s0 += __shfl_xor(s0, 16);
      s0 += __shfl_xor(s0, 32);
      if (lh == 0) wsum[w][brow] = s0;
    }
    if (act) elem(zb4, c1, h1c);
    __syncthreads();  // BAR1

    // -------- Phase B --------
    if (act) {
      if (t + 1 < 127) gather(t + 1);
      zacc();
#pragma unroll
      for (int kc = 0; kc < 4; ++kc) {
        bf16x8 x0 = ldB(h1c, kc);
        bf16x8 y0 = ldB(h2L, kc);
#pragma unroll
        for (int gg = 0; gg < 4; ++gg) {
          bf16x8 a = *(const bf16x8*)(g_wih2bf + (size_t)(gg * 128 + col) * 128 + kc * 32 + koff);
          bf16x8 a2 = *(const bf16x8*)(g_whhbf + 512 * 128 +
                                       (size_t)(gg * 128 + col) * 128 + kc * 32 + koff);
          acc[gg] = __builtin_amdgcn_mfma_f32_16x16x32_bf16(a, x0, acc[gg], 0, 0, 0);
          acc[gg] = __builtin_amdgcn_mfma_f32_16x16x32_bf16(a2, y0, acc[gg], 0, 0, 0);
        }
      }
    }
    if (pend) {  // ll-update(t-1): logits(t-1) predict token t
      int tgt = (int)tokL[t][brow];
      if ((tgt >> 4) == w && ((tgt >> 2) & 3) == lh) {
        int j = tgt & 3;
        float lvs = (j & 2) ? ((j & 1) ? lv[3] : lv[2]) : ((j & 1) ? lv[1] : lv[0]);
        float S = 0.f;
#pragma unroll
        for (int ww = 0; ww < 8; ++ww) S += wsum[ww][brow];
        llL[brow] += lvs - flog2(S);
      }
    }
    __syncthreads();  // BAR2

    // -------- Phase C --------
    if (act) elem(bias2v4, c2, h2L);
    __syncthreads();  // BAR3
  }

  if (tid < 16) out[b0 + tid] = llL[tid] * LN2;
}

extern "C" void kernel_launch(void* const* d_in, const int* in_sizes, int n_in,
                              void* d_out, int out_size, void* d_ws, size_t ws_size,
                              hipStream_t stream) {
  const float* state  = (const float*)d_in[0];
  const int*   tokens = (const int*)d_in[1];
  const float* emb    = (const float*)d_in[2];
  const float* Wih    = (const float*)d_in[3];
  const float* Whh    = (const float*)d_in[4];
  const float* bih    = (const float*)d_in[5];
  const float* bhh    = (const float*)d_in[6];
  const float* Wout   = (const float*)d_in[7];
  const float* bout   = (const float*)d_in[8];
  float* out = (float*)d_out;

  prep_emb1<<<16, 512, 0, stream>>>(emb, Wih, bih, bhh, Wout, Whh);
  lstm_ll<<<512, 512, 0, stream>>>(state, tokens, Wih, bih, bhh, bout, out);
}

// Round 10
// 1223.251 us; speedup vs baseline: 3.3572x; 3.3572x over previous
//
#include <hip/hip_runtime.h>
#include <hip/hip_bf16.h>

// LSTM-LL v10: time-serial layer split. K1 runs the layer-1 recurrence with
// whh1 fully in LDS (no global loads on the chain), streaming h1(t) to a
// global buffer. K2 runs layer-2 + logits + ll with whh2 in LDS; the
// non-recurrent wih2@h1(t) part streams from L2 (latency-tolerant).
// B=8192, T=128, E=128, V=128, L=2. Both kernels: 256 blocks x 512 thr.

typedef __bf16 bf16x8 __attribute__((ext_vector_type(8)));
typedef __bf16 bf16x4 __attribute__((ext_vector_type(4)));
typedef float  f32x4  __attribute__((ext_vector_type(4)));

#define LOG2E 1.4426950408889634f
#define LN2   0.6931471805599453f

static __device__ __bf16 g_emb1[128 * 512];    // [v][gate*128+e] = (emb@Wih1^T + b1)*rowscale
static __device__ __bf16 g_woutbf[128 * 128];  // [v][e] * LOG2E
static __device__ __bf16 g_wih2bf[512 * 128];  // [gate*128+col][k] * rowscale (layer 2 Wih)
static __device__ __bf16 g_h1[(size_t)128 * 8192 * 128];  // h1 stream: slot 0 = h1init, slot t+1 = h1(t)

__device__ __forceinline__ float frcp(float x) {
#if __has_builtin(__builtin_amdgcn_rcpf)
  return __builtin_amdgcn_rcpf(x);
#else
  return 1.0f / x;
#endif
}
__device__ __forceinline__ float fexp2(float x) {
#if __has_builtin(__builtin_amdgcn_exp2f)
  return __builtin_amdgcn_exp2f(x);
#else
  return exp2f(x);
#endif
}
__device__ __forceinline__ float flog2(float x) {
#if __has_builtin(__builtin_amdgcn_logf)
  return __builtin_amdgcn_logf(x);
#else
  return log2f(x);
#endif
}

// rotation swizzle for [*][128] bf16 LDS tiles: e -> (e + 8*(row&15)) & 127
__device__ __forceinline__ int hoff(int row, int e) {
  return row * 128 + ((e + ((row & 15) << 3)) & 127);
}

__global__ void prep_emb1(const float* __restrict__ emb, const float* __restrict__ Wih,
                          const float* __restrict__ bih, const float* __restrict__ bhh,
                          const float* __restrict__ Wout) {
  __shared__ float embS[128 * 128];
  __shared__ float wS[32 * 128];
  const int tid = threadIdx.x, bc = blockIdx.x;
  for (int i = tid; i < 128 * 32; i += 512) ((f32x4*)embS)[i] = ((const f32x4*)emb)[i];
  for (int i = tid; i < 32 * 32; i += 512)
    ((f32x4*)wS)[i] = ((const f32x4*)(Wih + bc * 32 * 128))[i];
  {  // bf16 W_out table (pre-scaled by log2e)
    int idx = bc * 512 + tid;
    g_woutbf[idx * 2]     = (__bf16)(Wout[idx * 2] * LOG2E);
    g_woutbf[idx * 2 + 1] = (__bf16)(Wout[idx * 2 + 1] * LOG2E);
  }
  // bf16 layer-2 Wih table, pre-scaled per gate (g-gate x2)
  for (int i = bc * 512 + tid; i < 512 * 128; i += 16 * 512) {
    int gate = (i >> 14) & 3;
    float sc = (gate == 2) ? 2.0f * LOG2E : LOG2E;
    g_wih2bf[i] = (__bf16)(Wih[512 * 128 + i] * sc);
  }
  __syncthreads();
  const int v = tid & 127, c0 = (tid >> 7) * 8;
  const int rot = v & 31;
#pragma unroll
  for (int j = 0; j < 8; ++j) {
    int c = c0 + j;
    float s = 0.f;
    for (int k = 0; k < 128; ++k) {
      int kk = (k + rot) & 127;
      s += embS[v * 128 + kk] * wS[c * 128 + kk];
    }
    int col = bc * 32 + c;
    float sc = ((col >> 7) == 2) ? 2.0f * LOG2E : LOG2E;
    g_emb1[v * 512 + col] = (__bf16)((s + bih[col] + bhh[col]) * sc);
  }
}

// ============================ K1: layer-1 recurrence ============================
__global__ __launch_bounds__(512, 2) void lstm_l1(
    const float* __restrict__ state, const int* __restrict__ tokens,
    const float* __restrict__ W_ih, const float* __restrict__ W_hh,
    const float* __restrict__ b_ih, const float* __restrict__ b_hh) {
  __shared__ __align__(16) __bf16 whh1L[512 * 128];  // 128 KB, hoff-swizzled
  __shared__ __align__(16) __bf16 h1L[2][32 * 128];  // 16 KB dbuf
  __shared__ unsigned char tokL[127][32];            // ~4 KB

  const int tid  = threadIdx.x;
  const int w    = tid >> 6;
  const int lane = tid & 63;
  const int lr   = lane & 15;
  const int lh   = lane >> 4;
  const int b0   = blockIdx.x * 32;
  const int col  = w * 16 + lr;
  const int koff = lh * 8;
  const int e0   = w * 16 + lh * 4;
  const float gscA[4] = {LOG2E, LOG2E, 2.0f * LOG2E, LOG2E};

  auto ldw8s = [&](const float* p, float sc) -> bf16x8 {
    f32x4 x0 = *(const f32x4*)p, x1 = *(const f32x4*)(p + 4);
    bf16x8 v;
#pragma unroll
    for (int j = 0; j < 4; ++j) { v[j] = (__bf16)(x0[j] * sc); v[4 + j] = (__bf16)(x1[j] * sc); }
    return v;
  };

  // stage whh1 (layer 0 of W_hh), f32 -> bf16 scaled, hoff layout
  for (int i = tid; i < 512 * 16; i += 512) {
    int row = i >> 4, e = (i & 15) * 8;
    *(bf16x8*)(whh1L + hoff(row, e)) = ldw8s(W_hh + row * 128 + e, gscA[row >> 7]);
  }
  for (int i = tid; i < 127 * 32; i += 512) {
    int r = i & 31, t = i >> 5;
    tokL[t][r] = (unsigned char)tokens[(b0 + r) * 128 + t];
  }

  f32x4 acc[4][2];
  float c1[2][4] = {};

  auto ldB = [&](const __bf16* buf, int nf, int kc) -> bf16x8 {
    return *(const bf16x8*)(buf + hoff(nf * 16 + lr, kc * 32 + koff));
  };

  // elem1: gates -> c,h ; write LDS (hoff) + global h1 stream (linear)
  auto elem1 = [&](const f32x4* b4, __bf16* hout, __bf16* gout) {
#pragma unroll
    for (int nf = 0; nf < 2; ++nf) {
      bf16x4 hp;
#pragma unroll
      for (int j = 0; j < 4; ++j) {
        float gi = acc[0][nf][j] + b4[0][j];
        float gf = acc[1][nf][j] + b4[1][j];
        float gc = acc[2][nf][j] + b4[2][j];
        float go = acc[3][nf][j] + b4[3][j];
        float sf = frcp(1.f + fexp2(-gf));
        float si = frcp(1.f + fexp2(-gi));
        float tg = 1.f - 2.f * frcp(fexp2(gc) + 1.f);
        float cc = sf * c1[nf][j] + si * tg;
        c1[nf][j] = cc;
        float so = frcp(1.f + fexp2(-go));
        float tc = 1.f - 2.f * frcp(fexp2(2.f * LOG2E * cc) + 1.f);
        hp[j] = (__bf16)(so * tc);
      }
      int b = nf * 16 + lr;
      *(bf16x4*)(hout + hoff(b, e0)) = hp;
      *(bf16x4*)(gout + (size_t)(b0 + b) * 128 + e0) = hp;
    }
  };
  const f32x4 zf4 = {0.f, 0.f, 0.f, 0.f};
  const f32x4 zb4[4] = {zf4, zf4, zf4, zf4};

  __syncthreads();  // staging complete

  bf16x4 gv[2][4];
  auto gather = [&](int t) {
#pragma unroll
    for (int nf = 0; nf < 2; ++nf) {
      int tk = (int)tokL[t][nf * 16 + lr];
      const __bf16* pp = g_emb1 + tk * 512 + e0;
#pragma unroll
      for (int gg = 0; gg < 4; ++gg) gv[nf][gg] = *(const bf16x4*)(pp + gg * 128);
    }
  };
  gather(0);

  // init: h1init = LSTM1(state, h=c=0) -> h1L[0] + g_h1 slot 0
  {
#pragma unroll
    for (int gg = 0; gg < 4; ++gg)
#pragma unroll
      for (int nf = 0; nf < 2; ++nf) acc[gg][nf] = zf4;
#pragma unroll
    for (int kc = 0; kc < 4; ++kc) {
      bf16x8 s0 = ldw8s(state + (size_t)(b0 + lr) * 128 + kc * 32 + koff, 1.0f);
      bf16x8 s1 = ldw8s(state + (size_t)(b0 + 16 + lr) * 128 + kc * 32 + koff, 1.0f);
#pragma unroll
      for (int gg = 0; gg < 4; ++gg) {
        bf16x8 a = ldw8s(W_ih + (gg * 128 + col) * 128 + kc * 32 + koff, gscA[gg]);
        acc[gg][0] = __builtin_amdgcn_mfma_f32_16x16x32_bf16(a, s0, acc[gg][0], 0, 0, 0);
        acc[gg][1] = __builtin_amdgcn_mfma_f32_16x16x32_bf16(a, s1, acc[gg][1], 0, 0, 0);
      }
    }
    f32x4 bias1v4[4];
#pragma unroll
    for (int gg = 0; gg < 4; ++gg)
#pragma unroll
      for (int j = 0; j < 4; ++j)
        bias1v4[gg][j] = (b_ih[gg * 128 + e0 + j] + b_hh[gg * 128 + e0 + j]) * gscA[gg];
    elem1(bias1v4, h1L[0], g_h1);
    __syncthreads();
  }

  // main loop: 1 barrier/step, all chain operands in LDS
#pragma unroll 1
  for (int t = 0; t < 127; ++t) {
    const __bf16* h1p = h1L[t & 1];
    __bf16* h1c = h1L[(t & 1) ^ 1];
    // acc init = gathered input gates (bias folded)
#pragma unroll
    for (int gg = 0; gg < 4; ++gg)
#pragma unroll
      for (int nf = 0; nf < 2; ++nf)
#pragma unroll
        for (int j = 0; j < 4; ++j) acc[gg][nf][j] = (float)gv[nf][gg][j];
#pragma unroll
    for (int kc = 0; kc < 4; ++kc) {
      bf16x8 p0 = ldB(h1p, 0, kc), p1 = ldB(h1p, 1, kc);
#pragma unroll
      for (int gg = 0; gg < 4; ++gg) {
        bf16x8 a = *(const bf16x8*)(whh1L + hoff(gg * 128 + col, kc * 32 + koff));
        acc[gg][0] = __builtin_amdgcn_mfma_f32_16x16x32_bf16(a, p0, acc[gg][0], 0, 0, 0);
        acc[gg][1] = __builtin_amdgcn_mfma_f32_16x16x32_bf16(a, p1, acc[gg][1], 0, 0, 0);
      }
    }
    if (t + 1 < 127) gather(t + 1);
    elem1(zb4, h1c, g_h1 + (size_t)(t + 1) * 8192 * 128);
    __syncthreads();
  }
}

// ==================== K2: layer-2 recurrence + logits + ll ====================
__global__ __launch_bounds__(512, 2) void lstm_l2(
    const int* __restrict__ tokens, const float* __restrict__ W_hh,
    const float* __restrict__ b_ih, const float* __restrict__ b_hh,
    const float* __restrict__ b_out, float* __restrict__ out) {
  __shared__ __align__(16) __bf16 whh2L[512 * 128];  // 128 KB, hoff
  __shared__ __align__(16) __bf16 h1S[32 * 128];     // 8 KB staged h1(t), hoff
  __shared__ __align__(16) __bf16 h2L[2][32 * 128];  // 16 KB dbuf, hoff
  __shared__ unsigned char tokL[128][32];            // 4 KB
  __shared__ float wsum[8][32];
  __shared__ float llL[32];

  const int tid  = threadIdx.x;
  const int w    = tid >> 6;
  const int lane = tid & 63;
  const int lr   = lane & 15;
  const int lh   = lane >> 4;
  const int b0   = blockIdx.x * 32;
  const int col  = w * 16 + lr;
  const int koff = lh * 8;
  const int e0   = w * 16 + lh * 4;
  const float gscA[4] = {LOG2E, LOG2E, 2.0f * LOG2E, LOG2E};

  auto ldw8s = [&](const float* p, float sc) -> bf16x8 {
    f32x4 x0 = *(const f32x4*)p, x1 = *(const f32x4*)(p + 4);
    bf16x8 v;
#pragma unroll
    for (int j = 0; j < 4; ++j) { v[j] = (__bf16)(x0[j] * sc); v[4 + j] = (__bf16)(x1[j] * sc); }
    return v;
  };

  // stage whh2 (layer 1 of W_hh)
  for (int i = tid; i < 512 * 16; i += 512) {
    int row = i >> 4, e = (i & 15) * 8;
    *(bf16x8*)(whh2L + hoff(row, e)) = ldw8s(W_hh + 512 * 128 + row * 128 + e, gscA[row >> 7]);
  }
  for (int i = tid; i < 128 * 32; i += 512) {
    int r = i & 31, t = i >> 5;
    tokL[t][r] = (unsigned char)tokens[(b0 + r) * 128 + t];
  }
  if (tid < 32) llL[tid] = 0.0f;

  // stage h1S = h1init (slot 0): linear global read -> hoff ds_write
  auto stageH1 = [&](int slot) {
    const __bf16* src = g_h1 + (size_t)slot * 8192 * 128 + (size_t)b0 * 128;
    int r = tid >> 4, e = (tid & 15) * 8;
    bf16x8 v = *(const bf16x8*)(src + r * 128 + e);
    *(bf16x8*)(h1S + hoff(r, e)) = v;
  };
  stageH1(0);

  f32x4 bias2v4[4], bo4;
#pragma unroll
  for (int gg = 0; gg < 4; ++gg)
#pragma unroll
    for (int j = 0; j < 4; ++j)
      bias2v4[gg][j] = (b_ih[512 + gg * 128 + e0 + j] + b_hh[512 + gg * 128 + e0 + j]) * gscA[gg];
#pragma unroll
  for (int j = 0; j < 4; ++j) bo4[j] = b_out[e0 + j] * LOG2E;

  float c2[2][4] = {};
  f32x4 acc[4][2];

  auto ldB = [&](const __bf16* buf, int nf, int kc) -> bf16x8 {
    return *(const bf16x8*)(buf + hoff(nf * 16 + lr, kc * 32 + koff));
  };

  auto elem2 = [&](__bf16* hout) {
#pragma unroll
    for (int nf = 0; nf < 2; ++nf) {
      bf16x4 hp;
#pragma unroll
      for (int j = 0; j < 4; ++j) {
        float gi = acc[0][nf][j] + bias2v4[0][j];
        float gf = acc[1][nf][j] + bias2v4[1][j];
        float gc = acc[2][nf][j] + bias2v4[2][j];
        float go = acc[3][nf][j] + bias2v4[3][j];
        float sf = frcp(1.f + fexp2(-gf));
        float si = frcp(1.f + fexp2(-gi));
        float tg = 1.f - 2.f * frcp(fexp2(gc) + 1.f);
        float cc = sf * c2[nf][j] + si * tg;
        c2[nf][j] = cc;
        float so = frcp(1.f + fexp2(-go));
        float tc = 1.f - 2.f * frcp(fexp2(2.f * LOG2E * cc) + 1.f);
        hp[j] = (__bf16)(so * tc);
      }
      int b = nf * 16 + lr;
      *(bf16x4*)(hout + hoff(b, e0)) = hp;
    }
  };
  const f32x4 zf4 = {0.f, 0.f, 0.f, 0.f};

  __syncthreads();  // staging complete (whh2L, h1S=slot0, tok)

  // init: h2init = LSTM2(h1init, h=c=0) -> h2L[1]
  {
#pragma unroll
    for (int gg = 0; gg < 4; ++gg)
#pragma unroll
      for (int nf = 0; nf < 2; ++nf) acc[gg][nf] = zf4;
#pragma unroll
    for (int kc = 0; kc < 4; ++kc) {
      bf16x8 x0 = ldB(h1S, 0, kc), x1 = ldB(h1S, 1, kc);
#pragma unroll
      for (int gg = 0; gg < 4; ++gg) {
        bf16x8 a = *(const bf16x8*)(g_wih2bf + (size_t)(gg * 128 + col) * 128 + kc * 32 + koff);
        acc[gg][0] = __builtin_amdgcn_mfma_f32_16x16x32_bf16(a, x0, acc[gg][0], 0, 0, 0);
        acc[gg][1] = __builtin_amdgcn_mfma_f32_16x16x32_bf16(a, x1, acc[gg][1], 0, 0, 0);
      }
    }
    __syncthreads();  // all h1S reads done before restage
    elem2(h2L[1]);
    stageH1(1);       // h1(0) for step t=0
    __syncthreads();  // publish h2L[1] + h1S
  }

  f32x4 lvA, lvB;

  // main loop: iter t: act = LSTM2 step t, pend = logits of step t-1
#pragma unroll 1
  for (int t = 0; t <= 127; ++t) {
    const bool act = (t < 127), pend = (t > 0);
    const __bf16* prev = h2L[(t + 1) & 1];
    __bf16* cur = h2L[t & 1];

    // -------- Phase A: wih2(t) [stream] + whh2(t) [LDS] + logits(t-1) + softmax --------
    f32x4 la0 = zf4, la1 = zf4;
    if (act) {
#pragma unroll
      for (int gg = 0; gg < 4; ++gg)
#pragma unroll
        for (int nf = 0; nf < 2; ++nf) acc[gg][nf] = zf4;
    }
#pragma unroll
    for (int kc = 0; kc < 4; ++kc) {
      if (act) {
        bf16x8 x0 = ldB(h1S, 0, kc), x1 = ldB(h1S, 1, kc);
#pragma unroll
        for (int gg = 0; gg < 4; ++gg) {
          bf16x8 a = *(const bf16x8*)(g_wih2bf + (size_t)(gg * 128 + col) * 128 + kc * 32 + koff);
          acc[gg][0] = __builtin_amdgcn_mfma_f32_16x16x32_bf16(a, x0, acc[gg][0], 0, 0, 0);
          acc[gg][1] = __builtin_amdgcn_mfma_f32_16x16x32_bf16(a, x1, acc[gg][1], 0, 0, 0);
        }
      }
      bf16x8 y0 = ldB(prev, 0, kc), y1 = ldB(prev, 1, kc);
      if (act) {
#pragma unroll
        for (int gg = 0; gg < 4; ++gg) {
          bf16x8 a2 = *(const bf16x8*)(whh2L + hoff(gg * 128 + col, kc * 32 + koff));
          acc[gg][0] = __builtin_amdgcn_mfma_f32_16x16x32_bf16(a2, y0, acc[gg][0], 0, 0, 0);
          acc[gg][1] = __builtin_amdgcn_mfma_f32_16x16x32_bf16(a2, y1, acc[gg][1], 0, 0, 0);
        }
      }
      if (pend) {
        bf16x8 wo = *(const bf16x8*)(g_woutbf + col * 128 + kc * 32 + koff);
        la0 = __builtin_amdgcn_mfma_f32_16x16x32_bf16(wo, y0, la0, 0, 0, 0);
        la1 = __builtin_amdgcn_mfma_f32_16x16x32_bf16(wo, y1, la1, 0, 0, 0);
      }
    }
    if (pend) {
      lvA = la0 + bo4;
      lvB = la1 + bo4;
      float s0 = fexp2(lvA[0]) + fexp2(lvA[1]) + fexp2(lvA[2]) + fexp2(lvA[3]);
      float s1 = fexp2(lvB[0]) + fexp2(lvB[1]) + fexp2(lvB[2]) + fexp2(lvB[3]);
      s0 += __shfl_xor(s0, 16); s0 += __shfl_xor(s0, 32);
      s1 += __shfl_xor(s1, 16); s1 += __shfl_xor(s1, 32);
      if (lh == 0) { wsum[w][lr] = s0; wsum[w][16 + lr] = s1; }
    }
    __syncthreads();  // BAR1: wsum ready; all h1S/prev reads done

    // -------- Phase B: ll-update(t-1) | elem2(t) -> cur | restage h1(t+1) --------
    if (pend) {
#pragma unroll
      for (int nf = 0; nf < 2; ++nf) {
        int r = nf * 16 + lr;
        int tgt = (int)tokL[t][r];
        if ((tgt >> 4) == w && ((tgt >> 2) & 3) == lh) {
          int j = tgt & 3;
          const f32x4& lv = nf ? lvB : lvA;
          float lvs = (j & 2) ? ((j & 1) ? lv[3] : lv[2]) : ((j & 1) ? lv[1] : lv[0]);
          float S = 0.f;
#pragma unroll
          for (int ww = 0; ww < 8; ++ww) S += wsum[ww][r];
          llL[r] += lvs - flog2(S);
        }
      }
    }
    if (act) elem2(cur);
    if (act && t <= 125) stageH1(t + 2);  // h1(t+1) = slot t+2
    __syncthreads();  // BAR2: publish cur + h1S
  }

  if (tid < 32) out[b0 + tid] = llL[tid] * LN2;
}

extern "C" void kernel_launch(void* const* d_in, const int* in_sizes, int n_in,
                              void* d_out, int out_size, void* d_ws, size_t ws_size,
                              hipStream_t stream) {
  const float* state  = (const float*)d_in[0];
  const int*   tokens = (const int*)d_in[1];
  const float* emb    = (const float*)d_in[2];
  const float* Wih    = (const float*)d_in[3];
  const float* Whh    = (const float*)d_in[4];
  const float* bih    = (const float*)d_in[5];
  const float* bhh    = (const float*)d_in[6];
  const float* Wout   = (const float*)d_in[7];
  const float* bout   = (const float*)d_in[8];
  float* out = (float*)d_out;

  prep_emb1<<<16, 512, 0, stream>>>(emb, Wih, bih, bhh, Wout);
  lstm_l1<<<256, 512, 0, stream>>>(state, tokens, Wih, Whh, bih, bhh);
  lstm_l2<<<256, 512, 0, stream>>>(tokens, Whh, bih, bhh, bout, out);
}